// Round 1
// baseline (1787.772 us; speedup 1.0000x reference)
//
#include <hip/hip_runtime.h>
#include <hip/hip_bf16.h>

#define NN 20000
#define EE 320000
#define RR 8

typedef float f32x4 __attribute__((ext_vector_type(4)));
typedef short s16x8 __attribute__((ext_vector_type(8)));

__device__ __forceinline__ unsigned short f2bf(float f) {
  unsigned u = __builtin_bit_cast(unsigned, f);
  unsigned r = u + 0x7FFFu + ((u >> 16) & 1u);
  return (unsigned short)(r >> 16);
}

// ---- per-(dst,relation) edge count (shared across layers of one graph) ----
__global__ void k_count(const int* __restrict__ dst, const int* __restrict__ et,
                        float* __restrict__ cnt, int E) {
  int e = blockIdx.x * blockDim.x + threadIdx.x;
  if (e < E) atomicAdd(&cnt[dst[e] * RR + et[e]], 1.0f);
}

// ---- scatter h[src]*inv into agg[etype][dst][*] ----
template <int CIN>
__global__ void k_agg(const int* __restrict__ src, const int* __restrict__ dst,
                      const int* __restrict__ et, const float* __restrict__ cnt,
                      const float* __restrict__ h, float* __restrict__ agg, int E) {
  int wave = threadIdx.x >> 6;
  int lane = threadIdx.x & 63;
  int e = blockIdx.x * 4 + wave;
  if (e >= E) return;
  int s = src[e], d = dst[e], t = et[e];
  float inv = 1.0f / fmaxf(cnt[d * RR + t], 1.0f);
  const float* hs = h + (size_t)s * CIN;
  float* ag = agg + ((size_t)t * NN + d) * CIN;
#pragma unroll
  for (int c = lane; c < CIN; c += 64) atomicAdd(&ag[c], hs[c] * inv);
}

// ---- build bf16 transposed weight panel BT[co][k], k = r*Cin+ci (r=8 -> root) ----
__global__ void k_bt(const float* __restrict__ W, const float* __restrict__ root,
                     unsigned short* __restrict__ bt, int Cin, int Cout, int Ktot) {
  int idx = blockIdx.x * blockDim.x + threadIdx.x;
  if (idx >= Cout * Ktot) return;
  int co = idx / Ktot, k = idx - co * Ktot;
  int r = k / Cin, ci = k - r * Cin;
  float v = (r < RR) ? W[((size_t)r * Cin + ci) * Cout + co]
                     : root[(size_t)ci * Cout + co];
  bt[idx] = f2bf(v);
}

// ---- GEMM: out[n,co] = lrelu( sum_k A[n,k]*BT[co,k] + bias[co] )
// A: k = r*Cin+ci ; r<8 from agg[r][n][ci], r==8 from hsrc[n][ci]
template <int CIN, int COUT>
__global__ __launch_bounds__(256) void k_gemm(
    const float* __restrict__ agg, const float* __restrict__ hsrc,
    const unsigned short* __restrict__ bt, const float* __restrict__ bias,
    float* __restrict__ out) {
  constexpr int KTOT = (RR + 1) * CIN;
  __shared__ unsigned short As[128][72];  // [m][k], +8 pad breaks bank conflicts
  __shared__ unsigned short Bs[128][72];  // [n][k]
  const int tid = threadIdx.x;
  const int lane = tid & 63;
  const int wave = tid >> 6;
  const int wm = (wave >> 1) * 64;
  const int wn = (wave & 1) * 64;
  const int m0 = blockIdx.x * 128;
  const int n0 = blockIdx.y * 128;

  f32x4 acc[4][4] = {};

  for (int k0 = 0; k0 < KTOT; k0 += 64) {
    const int r = k0 / CIN;
    const int ci0 = k0 - r * CIN;
    const float* Ab = (r < RR) ? (agg + (size_t)r * NN * CIN + ci0) : (hsrc + ci0);
    // stage A tile: 128 rows x 64 k, fp32 -> bf16
#pragma unroll
    for (int i = 0; i < 8; ++i) {
      int flat = tid + i * 256;           // float4 units, 2048 total
      int row = flat >> 4;
      int kk = (flat & 15) * 4;
      int gr = m0 + row;
      gr = gr < NN ? gr : NN - 1;         // clamp: garbage rows never stored
      const float4 v = *(const float4*)&Ab[(size_t)gr * CIN + kk];
      ushort4 w;
      w.x = f2bf(v.x); w.y = f2bf(v.y); w.z = f2bf(v.z); w.w = f2bf(v.w);
      *(ushort4*)&As[row][kk] = w;
    }
    // stage B tile: 128 out-cols x 64 k (already bf16)
#pragma unroll
    for (int i = 0; i < 4; ++i) {
      int flat = tid + i * 256;           // 8-bf16 units, 1024 total
      int row = flat >> 3;
      int kk = (flat & 7) * 8;
      const s16x8 v = *(const s16x8*)&bt[(size_t)(n0 + row) * KTOT + k0 + kk];
      *(s16x8*)&Bs[row][kk] = v;
    }
    __syncthreads();
#pragma unroll
    for (int kk = 0; kk < 2; ++kk) {
      s16x8 a[4], b[4];
#pragma unroll
      for (int f = 0; f < 4; ++f)
        a[f] = *(const s16x8*)&As[wm + f * 16 + (lane & 15)][kk * 32 + (lane >> 4) * 8];
#pragma unroll
      for (int f = 0; f < 4; ++f)
        b[f] = *(const s16x8*)&Bs[wn + f * 16 + (lane & 15)][kk * 32 + (lane >> 4) * 8];
#pragma unroll
      for (int fm = 0; fm < 4; ++fm)
#pragma unroll
        for (int fn = 0; fn < 4; ++fn)
          acc[fm][fn] = __builtin_amdgcn_mfma_f32_16x16x32_bf16(
              a[fm], b[fn], acc[fm][fn], 0, 0, 0);
    }
    __syncthreads();
  }
  // epilogue: + bias, LeakyReLU(0.2), fp32 store
#pragma unroll
  for (int fm = 0; fm < 4; ++fm) {
    int rbase = m0 + wm + fm * 16 + (lane >> 4) * 4;
#pragma unroll
    for (int fn = 0; fn < 4; ++fn) {
      int col = n0 + wn + fn * 16 + (lane & 15);
      float bv = bias[col];
#pragma unroll
      for (int v = 0; v < 4; ++v) {
        int row = rbase + v;
        if (row < NN) {
          float xv = acc[fm][fn][v] + bv;
          out[(size_t)row * COUT + col] = xv > 0.f ? xv : 0.2f * xv;
        }
      }
    }
  }
}

extern "C" void kernel_launch(void* const* d_in, const int* in_sizes, int n_in,
                              void* d_out, int out_size, void* d_ws, size_t ws_size,
                              hipStream_t stream) {
  const float* x  = (const float*)d_in[0];
  const int* ei   = (const int*)d_in[1];
  const int* etp_ = (const int*)d_in[2];
  const float* W0 = (const float*)d_in[3];
  const float* r0 = (const float*)d_in[4];
  const float* b0 = (const float*)d_in[5];
  const float* W1 = (const float*)d_in[6];
  const float* r1 = (const float*)d_in[7];
  const float* b1 = (const float*)d_in[8];
  const float* W2 = (const float*)d_in[9];
  const float* r2 = (const float*)d_in[10];
  const float* b2 = (const float*)d_in[11];

  float* agg = (float*)d_ws;                         // 8*NN*256 f32 (164 MB)
  float* h_a = agg + (size_t)8 * NN * 256;           // NN*256
  float* h_b = h_a + (size_t)NN * 256;               // NN*256
  float* cnt = h_b + (size_t)NN * 256;               // NN*8
  unsigned short* bt0 = (unsigned short*)(cnt + (size_t)NN * RR);
  unsigned short* bt1 = bt0 + (size_t)256 * 1152;
  unsigned short* bt2 = bt1 + (size_t)256 * 2304;
  float* outf = (float*)d_out;

  // bf16 weight panels (shared by both graphs)
  k_bt<<<(256 * 1152 + 255) / 256, 256, 0, stream>>>(W0, r0, bt0, 128, 256, 1152);
  k_bt<<<(256 * 2304 + 255) / 256, 256, 0, stream>>>(W1, r1, bt1, 256, 256, 2304);
  k_bt<<<(128 * 2304 + 255) / 256, 256, 0, stream>>>(W2, r2, bt2, 256, 128, 2304);

  for (int g = 0; g < 2; ++g) {
    const int* srcp = ei + (size_t)g * 2 * EE;
    const int* dstp = srcp + EE;
    const int* etp = etp_ + (size_t)g * EE;
    const float* xg = x + (size_t)g * NN * 128;

    hipMemsetAsync(cnt, 0, (size_t)NN * RR * 4, stream);
    k_count<<<EE / 256, 256, 0, stream>>>(dstp, etp, cnt, EE);

    // layer 0: Cin=128 -> Cout=256
    hipMemsetAsync(agg, 0, (size_t)8 * NN * 128 * 4, stream);
    k_agg<128><<<EE / 4, 256, 0, stream>>>(srcp, dstp, etp, cnt, xg, agg, EE);
    k_gemm<128, 256><<<dim3(157, 2), 256, 0, stream>>>(agg, xg, bt0, b0, h_a);

    // layer 1: 256 -> 256
    hipMemsetAsync(agg, 0, (size_t)8 * NN * 256 * 4, stream);
    k_agg<256><<<EE / 4, 256, 0, stream>>>(srcp, dstp, etp, cnt, h_a, agg, EE);
    k_gemm<256, 256><<<dim3(157, 2), 256, 0, stream>>>(agg, h_a, bt1, b1, h_b);

    // layer 2: 256 -> 128
    hipMemsetAsync(agg, 0, (size_t)8 * NN * 256 * 4, stream);
    k_agg<256><<<EE / 4, 256, 0, stream>>>(srcp, dstp, etp, cnt, h_b, agg, EE);
    k_gemm<256, 128><<<dim3(157, 1), 256, 0, stream>>>(agg, h_b, bt2, b2,
                                                       outf + (size_t)g * NN * 128);
  }
}

// Round 2
// 730.842 us; speedup vs baseline: 2.4462x; 2.4462x over previous
//
#include <hip/hip_runtime.h>
#include <hip/hip_bf16.h>

#define NN 20000
#define EE 320000
#define RR 8

typedef float f32x4 __attribute__((ext_vector_type(4)));
typedef short s16x8 __attribute__((ext_vector_type(8)));

__device__ __forceinline__ unsigned short f2bf(float f) {
  unsigned u = __builtin_bit_cast(unsigned, f);
  unsigned r = u + 0x7FFFu + ((u >> 16) & 1u);
  return (unsigned short)(r >> 16);
}
__device__ __forceinline__ float bf2f(unsigned short u) {
  return __builtin_bit_cast(float, (unsigned)u << 16);
}

// ---- per-(dst,relation) segment count ----
__global__ void k_count(const int* __restrict__ dst, const int* __restrict__ et,
                        int* __restrict__ cnt, int E) {
  int e = blockIdx.x * blockDim.x + threadIdx.x;
  if (e < E) atomicAdd(&cnt[dst[e] * RR + et[e]], 1);
}

// ---- exclusive scan over n=160000 counts, single block 1024 thr x 4 elem ----
__global__ __launch_bounds__(1024) void k_scan(const int* __restrict__ cnt,
                                               int* __restrict__ off, int n) {
  __shared__ int wsum[16];
  __shared__ int carry_s;
  if (threadIdx.x == 0) carry_s = 0;
  __syncthreads();
  int lane = threadIdx.x & 63, w = threadIdx.x >> 6;
  for (int base = 0; base < n; base += 4096) {
    int i = base + (int)threadIdx.x * 4;
    int4 v = {0, 0, 0, 0};
    if (i + 3 < n) v = *(const int4*)&cnt[i];
    else {
      if (i < n) v.x = cnt[i];
      if (i + 1 < n) v.y = cnt[i + 1];
      if (i + 2 < n) v.z = cnt[i + 2];
      if (i + 3 < n) v.w = cnt[i + 3];
    }
    int s0 = v.x, s1 = s0 + v.y, s2 = s1 + v.z, s3 = s2 + v.w;
    int s = s3;
    for (int d = 1; d < 64; d <<= 1) {
      int t = __shfl_up(s, d);
      if (lane >= d) s += t;
    }
    if (lane == 63) wsum[w] = s;
    __syncthreads();
    if (threadIdx.x < 16) {
      int ws = wsum[threadIdx.x];
      for (int d = 1; d < 16; d <<= 1) {
        int t = __shfl_up(ws, d);
        if ((int)threadIdx.x >= d) ws += t;
      }
      wsum[threadIdx.x] = ws;
    }
    __syncthreads();
    int carry = carry_s;
    int wexcl = (w > 0) ? wsum[w - 1] : 0;
    int excl = carry + wexcl + (s - s3);
    if (i < n) off[i] = excl;
    if (i + 1 < n) off[i + 1] = excl + s0;
    if (i + 2 < n) off[i + 2] = excl + s1;
    if (i + 3 < n) off[i + 3] = excl + s2;
    __syncthreads();
    if (threadIdx.x == 0) carry_s = carry + wsum[15];
    __syncthreads();
  }
  if (threadIdx.x == 0) off[n] = carry_s;
}

// ---- scatter src ids into segment-sorted order ----
__global__ void k_scatter(const int* __restrict__ src, const int* __restrict__ dst,
                          const int* __restrict__ et, const int* __restrict__ off,
                          int* __restrict__ cur, int* __restrict__ ssrc, int E) {
  int e = blockIdx.x * blockDim.x + threadIdx.x;
  if (e >= E) return;
  int seg = dst[e] * RR + et[e];
  int pos = off[seg] + atomicAdd(&cur[seg], 1);
  ssrc[pos] = src[e];
}

// ---- fp32 x -> bf16 ----
__global__ void k_cvt(const float* __restrict__ in, unsigned short* __restrict__ out,
                      int n) {
  int i = (blockIdx.x * blockDim.x + threadIdx.x) * 4;
  if (i + 3 < n) {
    float4 v = *(const float4*)&in[i];
    ushort4 o;
    o.x = f2bf(v.x); o.y = f2bf(v.y); o.z = f2bf(v.z); o.w = f2bf(v.w);
    *(ushort4*)&out[i] = o;
  } else {
    for (int j = i; j < n; ++j) out[j] = f2bf(in[j]);
  }
}

// ---- gather: one wave per dst node; per-relation mean -> agg[r][dst][*] bf16 ----
template <int CIN>
__global__ __launch_bounds__(256) void k_gather(
    const int* __restrict__ ssrc, const int* __restrict__ off,
    const unsigned short* __restrict__ h, unsigned short* __restrict__ agg) {
  constexpr int V = CIN / 64;  // bf16 per lane (2 or 4)
  int wave = threadIdx.x >> 6, lane = threadIdx.x & 63;
  int d = blockIdx.x * 4 + wave;
  if (d >= NN) return;
  const int c0 = lane * V;
  int o0 = off[d * RR];
#pragma unroll
  for (int r = 0; r < RR; ++r) {
    int o1 = off[d * RR + r + 1];
    float acc[V] = {};
    int e = o0;
    for (; e + 1 < o1; e += 2) {  // 2-deep for load overlap
      int sa = ssrc[e], sb = ssrc[e + 1];
      if constexpr (V == 4) {
        ushort4 ha = *(const ushort4*)&h[(size_t)sa * CIN + c0];
        ushort4 hb = *(const ushort4*)&h[(size_t)sb * CIN + c0];
        acc[0] += bf2f(ha.x) + bf2f(hb.x);
        acc[1] += bf2f(ha.y) + bf2f(hb.y);
        acc[2] += bf2f(ha.z) + bf2f(hb.z);
        acc[3] += bf2f(ha.w) + bf2f(hb.w);
      } else {
        ushort2 ha = *(const ushort2*)&h[(size_t)sa * CIN + c0];
        ushort2 hb = *(const ushort2*)&h[(size_t)sb * CIN + c0];
        acc[0] += bf2f(ha.x) + bf2f(hb.x);
        acc[1] += bf2f(ha.y) + bf2f(hb.y);
      }
    }
    if (e < o1) {
      int sa = ssrc[e];
      if constexpr (V == 4) {
        ushort4 ha = *(const ushort4*)&h[(size_t)sa * CIN + c0];
        acc[0] += bf2f(ha.x); acc[1] += bf2f(ha.y);
        acc[2] += bf2f(ha.z); acc[3] += bf2f(ha.w);
      } else {
        ushort2 ha = *(const ushort2*)&h[(size_t)sa * CIN + c0];
        acc[0] += bf2f(ha.x); acc[1] += bf2f(ha.y);
      }
    }
    float inv = 1.0f / fmaxf((float)(o1 - o0), 1.0f);
    unsigned short* ap = agg + ((size_t)r * NN + d) * CIN + c0;
    if constexpr (V == 4) {
      ushort4 o;
      o.x = f2bf(acc[0] * inv); o.y = f2bf(acc[1] * inv);
      o.z = f2bf(acc[2] * inv); o.w = f2bf(acc[3] * inv);
      *(ushort4*)ap = o;
    } else {
      ushort2 o;
      o.x = f2bf(acc[0] * inv); o.y = f2bf(acc[1] * inv);
      *(ushort2*)ap = o;
    }
    o0 = o1;
  }
}

// ---- bf16 transposed weight panel BT[co][k], k = r*Cin+ci (r=8 -> root) ----
__global__ void k_bt(const float* __restrict__ W, const float* __restrict__ root,
                     unsigned short* __restrict__ bt, int Cin, int Cout, int Ktot) {
  int idx = blockIdx.x * blockDim.x + threadIdx.x;
  if (idx >= Cout * Ktot) return;
  int co = idx / Ktot, k = idx - co * Ktot;
  int r = k / Cin, ci = k - r * Cin;
  float v = (r < RR) ? W[((size_t)r * Cin + ci) * Cout + co]
                     : root[(size_t)ci * Cout + co];
  bt[idx] = f2bf(v);
}

// ---- GEMM: out[n,co] = lrelu( sum_k A[n,k]*BT[co,k] + bias[co] ) ----
template <int CIN, int COUT, bool OUTF32>
__global__ __launch_bounds__(256) void k_gemm(
    const unsigned short* __restrict__ agg, const unsigned short* __restrict__ hsrc,
    const unsigned short* __restrict__ bt, const float* __restrict__ bias,
    void* __restrict__ outp) {
  constexpr int KTOT = (RR + 1) * CIN;
  __shared__ unsigned short As[128][72];
  __shared__ unsigned short Bs[128][72];
  const int tid = threadIdx.x;
  const int lane = tid & 63;
  const int wave = tid >> 6;
  const int wm = (wave >> 1) * 64;
  const int wn = (wave & 1) * 64;
  const int m0 = blockIdx.x * 128;
  const int n0 = blockIdx.y * 128;

  f32x4 acc[4][4] = {};

  for (int k0 = 0; k0 < KTOT; k0 += 64) {
    const int r = k0 / CIN;
    const int ci0 = k0 - r * CIN;
    const unsigned short* Ab =
        (r < RR) ? (agg + (size_t)r * NN * CIN + ci0) : (hsrc + ci0);
#pragma unroll
    for (int i = 0; i < 4; ++i) {
      int flat = tid + i * 256;
      int row = flat >> 3;
      int kk = (flat & 7) * 8;
      int gr = m0 + row;
      gr = gr < NN ? gr : NN - 1;
      *(s16x8*)&As[row][kk] = *(const s16x8*)&Ab[(size_t)gr * CIN + kk];
    }
#pragma unroll
    for (int i = 0; i < 4; ++i) {
      int flat = tid + i * 256;
      int row = flat >> 3;
      int kk = (flat & 7) * 8;
      *(s16x8*)&Bs[row][kk] =
          *(const s16x8*)&bt[(size_t)(n0 + row) * KTOT + k0 + kk];
    }
    __syncthreads();
#pragma unroll
    for (int kk = 0; kk < 2; ++kk) {
      s16x8 a[4], b[4];
#pragma unroll
      for (int f = 0; f < 4; ++f)
        a[f] = *(const s16x8*)&As[wm + f * 16 + (lane & 15)][kk * 32 + (lane >> 4) * 8];
#pragma unroll
      for (int f = 0; f < 4; ++f)
        b[f] = *(const s16x8*)&Bs[wn + f * 16 + (lane & 15)][kk * 32 + (lane >> 4) * 8];
#pragma unroll
      for (int fm = 0; fm < 4; ++fm)
#pragma unroll
        for (int fn = 0; fn < 4; ++fn)
          acc[fm][fn] = __builtin_amdgcn_mfma_f32_16x16x32_bf16(
              a[fm], b[fn], acc[fm][fn], 0, 0, 0);
    }
    __syncthreads();
  }
#pragma unroll
  for (int fm = 0; fm < 4; ++fm) {
    int rbase = m0 + wm + fm * 16 + (lane >> 4) * 4;
#pragma unroll
    for (int fn = 0; fn < 4; ++fn) {
      int col = n0 + wn + fn * 16 + (lane & 15);
      float bv = bias[col];
#pragma unroll
      for (int v = 0; v < 4; ++v) {
        int row = rbase + v;
        if (row < NN) {
          float xv = acc[fm][fn][v] + bv;
          xv = xv > 0.f ? xv : 0.2f * xv;
          if constexpr (OUTF32)
            ((float*)outp)[(size_t)row * COUT + col] = xv;
          else
            ((unsigned short*)outp)[(size_t)row * COUT + col] = f2bf(xv);
        }
      }
    }
  }
}

extern "C" void kernel_launch(void* const* d_in, const int* in_sizes, int n_in,
                              void* d_out, int out_size, void* d_ws, size_t ws_size,
                              hipStream_t stream) {
  const float* x  = (const float*)d_in[0];
  const int* ei   = (const int*)d_in[1];
  const int* etp_ = (const int*)d_in[2];
  const float* W0 = (const float*)d_in[3];
  const float* r0 = (const float*)d_in[4];
  const float* b0 = (const float*)d_in[5];
  const float* W1 = (const float*)d_in[6];
  const float* r1 = (const float*)d_in[7];
  const float* b1 = (const float*)d_in[8];
  const float* W2 = (const float*)d_in[9];
  const float* r2 = (const float*)d_in[10];
  const float* b2 = (const float*)d_in[11];

  char* p = (char*)d_ws;
  unsigned short* agg = (unsigned short*)p; p += (size_t)8 * NN * 256 * 2;   // 82 MB
  unsigned short* h0  = (unsigned short*)p; p += (size_t)NN * 128 * 2;       // x bf16
  unsigned short* h_a = (unsigned short*)p; p += (size_t)NN * 256 * 2;
  unsigned short* h_b = (unsigned short*)p; p += (size_t)NN * 256 * 2;
  int* cnt  = (int*)p; p += (size_t)NN * RR * 4;
  int* off  = (int*)p; p += (size_t)(NN * RR + 4) * 4;
  int* cur  = (int*)p; p += (size_t)NN * RR * 4;
  int* ssrc = (int*)p; p += (size_t)EE * 4;
  unsigned short* bt0 = (unsigned short*)p; p += (size_t)256 * 1152 * 2;
  unsigned short* bt1 = (unsigned short*)p; p += (size_t)256 * 2304 * 2;
  unsigned short* bt2 = (unsigned short*)p; p += (size_t)128 * 2304 * 2;
  float* outf = (float*)d_out;

  k_bt<<<(256 * 1152 + 255) / 256, 256, 0, stream>>>(W0, r0, bt0, 128, 256, 1152);
  k_bt<<<(256 * 2304 + 255) / 256, 256, 0, stream>>>(W1, r1, bt1, 256, 256, 2304);
  k_bt<<<(128 * 2304 + 255) / 256, 256, 0, stream>>>(W2, r2, bt2, 256, 128, 2304);

  for (int g = 0; g < 2; ++g) {
    const int* srcp = ei + (size_t)g * 2 * EE;
    const int* dstp = srcp + EE;
    const int* etp = etp_ + (size_t)g * EE;
    const float* xg = x + (size_t)g * NN * 128;

    // sort edges by (dst, etype)
    hipMemsetAsync(cnt, 0, (size_t)NN * RR * 4, stream);
    hipMemsetAsync(cur, 0, (size_t)NN * RR * 4, stream);
    k_count<<<EE / 256, 256, 0, stream>>>(dstp, etp, cnt, EE);
    k_scan<<<1, 1024, 0, stream>>>(cnt, off, NN * RR);
    k_scatter<<<EE / 256, 256, 0, stream>>>(srcp, dstp, etp, off, cur, ssrc, EE);
    k_cvt<<<(NN * 128 / 4 + 255) / 256, 256, 0, stream>>>(xg, h0, NN * 128);

    // layer 0: 128 -> 256
    k_gather<128><<<(NN + 3) / 4, 256, 0, stream>>>(ssrc, off, h0, agg);
    k_gemm<128, 256, false><<<dim3(157, 2), 256, 0, stream>>>(agg, h0, bt0, b0, h_a);

    // layer 1: 256 -> 256
    k_gather<256><<<(NN + 3) / 4, 256, 0, stream>>>(ssrc, off, h_a, agg);
    k_gemm<256, 256, false><<<dim3(157, 2), 256, 0, stream>>>(agg, h_a, bt1, b1, h_b);

    // layer 2: 256 -> 128
    k_gather<256><<<(NN + 3) / 4, 256, 0, stream>>>(ssrc, off, h_b, agg);
    k_gemm<256, 128, true><<<dim3(157, 1), 256, 0, stream>>>(
        agg, h_b, bt2, b2, outf + (size_t)g * NN * 128);
  }
}

// Round 3
// 437.467 us; speedup vs baseline: 4.0866x; 1.6706x over previous
//
#include <hip/hip_runtime.h>
#include <hip/hip_bf16.h>

#define NN 20000
#define EE 320000
#define RR 8
#define NR (NN * RR)
#define NB 40  // scan blocks per graph: ceil(160000/4096)

typedef float f32x4 __attribute__((ext_vector_type(4)));
typedef short s16x8 __attribute__((ext_vector_type(8)));

__device__ __forceinline__ unsigned short f2bf(float f) {
  unsigned u = __builtin_bit_cast(unsigned, f);
  unsigned r = u + 0x7FFFu + ((u >> 16) & 1u);
  return (unsigned short)(r >> 16);
}
__device__ __forceinline__ float bf2f(unsigned short u) {
  return __builtin_bit_cast(float, (unsigned)u << 16);
}
__device__ __forceinline__ void gload_lds16(const void* g, void* l) {
  __builtin_amdgcn_global_load_lds(
      (const __attribute__((address_space(1))) unsigned*)g,
      (__attribute__((address_space(3))) unsigned*)l, 16, 0, 0);
}

// ---- per-(graph,dst,relation) segment count, both graphs ----
__global__ void k_count(const int* __restrict__ ei, const int* __restrict__ et,
                        int* __restrict__ cnt) {
  int e = blockIdx.x * blockDim.x + threadIdx.x;  // 0..2*EE
  int g = e >= EE;
  int el = e - g * EE;
  int d = ei[(size_t)g * 2 * EE + EE + el];
  int t = et[(size_t)g * EE + el];
  atomicAdd(&cnt[(size_t)g * NR + d * RR + t], 1);
}

// ---- hierarchical exclusive scan: local scan + block totals ----
__global__ __launch_bounds__(1024) void k_scan1(const int* __restrict__ cnt,
                                                int* __restrict__ off,
                                                int* __restrict__ btot) {
  int g = blockIdx.y, b = blockIdx.x;
  const int* c = cnt + (size_t)g * NR;
  int* o = off + (size_t)g * NR;
  __shared__ int wsum[16];
  int lane = threadIdx.x & 63, w = threadIdx.x >> 6;
  int i = b * 4096 + (int)threadIdx.x * 4;
  int4 v = {0, 0, 0, 0};
  if (i + 3 < NR) v = *(const int4*)&c[i];
  else {
    if (i < NR) v.x = c[i];
    if (i + 1 < NR) v.y = c[i + 1];
    if (i + 2 < NR) v.z = c[i + 2];
  }
  int s0 = v.x, s1 = s0 + v.y, s2 = s1 + v.z, s3 = s2 + v.w;
  int s = s3;
  for (int d = 1; d < 64; d <<= 1) {
    int t = __shfl_up(s, d);
    if (lane >= d) s += t;
  }
  if (lane == 63) wsum[w] = s;
  __syncthreads();
  if (threadIdx.x < 16) {
    int ws = wsum[threadIdx.x];
    for (int d = 1; d < 16; d <<= 1) {
      int t = __shfl_up(ws, d);
      if ((int)threadIdx.x >= d) ws += t;
    }
    wsum[threadIdx.x] = ws;
  }
  __syncthreads();
  int excl = (w > 0 ? wsum[w - 1] : 0) + (s - s3);
  if (i < NR) o[i] = excl;
  if (i + 1 < NR) o[i + 1] = excl + s0;
  if (i + 2 < NR) o[i + 2] = excl + s1;
  if (i + 3 < NR) o[i + 3] = excl + s2;
  if (threadIdx.x == 0) btot[g * NB + b] = wsum[15];
}

// ---- scan of the 2x40 block totals (one wave per graph) ----
__global__ void k_scan2(const int* __restrict__ btot, int* __restrict__ bof) {
  int g = threadIdx.x >> 6, lane = threadIdx.x & 63;
  int v = (lane < NB) ? btot[g * NB + lane] : 0;
  int s = v;
  for (int d = 1; d < 64; d <<= 1) {
    int t = __shfl_up(s, d);
    if (lane >= d) s += t;
  }
  if (lane < NB) bof[g * NB + lane] = s - v;
}

// ---- add block offsets ----
__global__ __launch_bounds__(1024) void k_scan3(int* __restrict__ off,
                                                const int* __restrict__ bof) {
  int g = blockIdx.y;
  int add = bof[g * NB + blockIdx.x];
  int i = blockIdx.x * 4096 + (int)threadIdx.x * 4;
  int* o = off + (size_t)g * NR;
  if (i + 3 < NR) {
    int4 v = *(const int4*)&o[i];
    v.x += add; v.y += add; v.z += add; v.w += add;
    *(int4*)&o[i] = v;
  } else {
    for (int j = i; j < NR; ++j) o[j] += add;
  }
}

// ---- scatter src ids; DESTROYS off: post-scatter off[s] = end of segment s ----
__global__ void k_scatter(const int* __restrict__ ei, const int* __restrict__ et,
                          int* __restrict__ off, int* __restrict__ ssrc) {
  int e = blockIdx.x * blockDim.x + threadIdx.x;
  int g = e >= EE;
  int el = e - g * EE;
  int s = ei[(size_t)g * 2 * EE + el];
  int d = ei[(size_t)g * 2 * EE + EE + el];
  int t = et[(size_t)g * EE + el];
  int pos = atomicAdd(&off[(size_t)g * NR + d * RR + t], 1);
  ssrc[(size_t)g * EE + pos] = s;
}

// ---- fp32 x -> bf16, both graphs, into per-graph NN*256-strided slots ----
__global__ void k_cvt(const float* __restrict__ x, unsigned short* __restrict__ hX) {
  int i = (blockIdx.x * blockDim.x + threadIdx.x) * 4;
  if (i >= 2 * NN * 128) return;
  int g = i >= NN * 128;
  int il = i - g * NN * 128;
  float4 v = *(const float4*)&x[i];
  ushort4 o;
  o.x = f2bf(v.x); o.y = f2bf(v.y); o.z = f2bf(v.z); o.w = f2bf(v.w);
  *(ushort4*)&hX[(size_t)g * NN * 256 + il] = o;
}

// ---- gather: one wave per dst node; per-relation mean -> agg[g][r][dst][*] ----
template <int CIN>
__global__ __launch_bounds__(256) void k_gather(
    const int* __restrict__ ssrc, const int* __restrict__ off,
    const unsigned short* __restrict__ h, unsigned short* __restrict__ agg) {
  constexpr int V = CIN / 64;
  int g = blockIdx.y;
  ssrc += (size_t)g * EE;
  off += (size_t)g * NR;
  h += (size_t)g * NN * 256;
  agg += (size_t)g * 8 * NN * CIN;
  int wave = threadIdx.x >> 6, lane = threadIdx.x & 63;
  int d = blockIdx.x * 4 + wave;
  if (d >= NN) return;
  const int c0 = lane * V;
  int seg0 = d * RR;
  int o0 = (seg0 == 0) ? 0 : off[seg0 - 1];
#pragma unroll
  for (int r = 0; r < RR; ++r) {
    int o1 = off[seg0 + r];
    float acc[V] = {};
    int e = o0;
    for (; e + 1 < o1; e += 2) {
      int sa = ssrc[e], sb = ssrc[e + 1];
      if constexpr (V == 4) {
        ushort4 ha = *(const ushort4*)&h[(size_t)sa * CIN + c0];
        ushort4 hb = *(const ushort4*)&h[(size_t)sb * CIN + c0];
        acc[0] += bf2f(ha.x) + bf2f(hb.x);
        acc[1] += bf2f(ha.y) + bf2f(hb.y);
        acc[2] += bf2f(ha.z) + bf2f(hb.z);
        acc[3] += bf2f(ha.w) + bf2f(hb.w);
      } else {
        ushort2 ha = *(const ushort2*)&h[(size_t)sa * CIN + c0];
        ushort2 hb = *(const ushort2*)&h[(size_t)sb * CIN + c0];
        acc[0] += bf2f(ha.x) + bf2f(hb.x);
        acc[1] += bf2f(ha.y) + bf2f(hb.y);
      }
    }
    if (e < o1) {
      int sa = ssrc[e];
      if constexpr (V == 4) {
        ushort4 ha = *(const ushort4*)&h[(size_t)sa * CIN + c0];
        acc[0] += bf2f(ha.x); acc[1] += bf2f(ha.y);
        acc[2] += bf2f(ha.z); acc[3] += bf2f(ha.w);
      } else {
        ushort2 ha = *(const ushort2*)&h[(size_t)sa * CIN + c0];
        acc[0] += bf2f(ha.x); acc[1] += bf2f(ha.y);
      }
    }
    float inv = 1.0f / fmaxf((float)(o1 - o0), 1.0f);
    unsigned short* ap = agg + ((size_t)r * NN + d) * CIN + c0;
    if constexpr (V == 4) {
      ushort4 o;
      o.x = f2bf(acc[0] * inv); o.y = f2bf(acc[1] * inv);
      o.z = f2bf(acc[2] * inv); o.w = f2bf(acc[3] * inv);
      *(ushort4*)ap = o;
    } else {
      ushort2 o;
      o.x = f2bf(acc[0] * inv); o.y = f2bf(acc[1] * inv);
      *(ushort2*)ap = o;
    }
    o0 = o1;
  }
}

// ---- bf16 transposed weight panel BT[co][k], k = r*Cin+ci (r=8 -> root) ----
__global__ void k_bt(const float* __restrict__ W, const float* __restrict__ root,
                     unsigned short* __restrict__ bt, int Cin, int Cout, int Ktot) {
  int idx = blockIdx.x * blockDim.x + threadIdx.x;
  if (idx >= Cout * Ktot) return;
  int co = idx / Ktot, k = idx - co * Ktot;
  int r = k / Cin, ci = k - r * Cin;
  float v = (r < RR) ? W[((size_t)r * Cin + ci) * Cout + co]
                     : root[(size_t)ci * Cout + co];
  bt[idx] = f2bf(v);
}

// ---- GEMM via global_load_lds + XOR-swizzled LDS; batched over graphs ----
template <int CIN, int COUT, bool OUTF32>
__global__ __launch_bounds__(256) void k_gemm(
    const unsigned short* __restrict__ agg, const unsigned short* __restrict__ hsrc,
    const unsigned short* __restrict__ bt, const float* __restrict__ bias,
    void* __restrict__ outp) {
  constexpr int KTOT = (RR + 1) * CIN;
  __shared__ unsigned short As[128 * 64];  // linear; storage swizzled by S(L)
  __shared__ unsigned short Bs[128 * 64];
  const int tid = threadIdx.x, lane = tid & 63, wave = tid >> 6;
  const int wm = (wave >> 1) * 64, wn = (wave & 1) * 64;
  const int m0 = blockIdx.x * 128, n0 = blockIdx.y * 128;
  const int g = blockIdx.z;
  agg += (size_t)g * 8 * NN * CIN;
  hsrc += (size_t)g * NN * 256;

  f32x4 acc[4][4] = {};

  for (int k0 = 0; k0 < KTOT; k0 += 64) {
    const int r = k0 / CIN, ci0 = k0 - r * CIN;
    const unsigned short* Ab =
        (r < RR) ? (agg + (size_t)r * NN * CIN + ci0) : (hsrc + ci0);
#pragma unroll
    for (int i = 0; i < 4; ++i) {
      int ldsb = (wave * 4 + i) * 1024;       // uniform within wave
      int Wb = ldsb + lane * 16;              // this lane's LDS dest byte
      int row = Wb >> 7;                      // row unchanged by swizzle
      int colb = (Wb & 127) ^ ((row & 7) << 4);  // inverse-swizzled source col
      int gr = m0 + row;
      gr = gr < NN ? gr : NN - 1;
      gload_lds16((const char*)Ab + ((size_t)gr * CIN) * 2 + colb,
                  (char*)As + ldsb);
      gload_lds16((const char*)bt + ((size_t)(n0 + row) * KTOT + k0) * 2 + colb,
                  (char*)Bs + ldsb);
    }
    __syncthreads();
#pragma unroll
    for (int kk = 0; kk < 2; ++kk) {
      s16x8 a[4], b[4];
#pragma unroll
      for (int f = 0; f < 4; ++f) {
        int row = wm + f * 16 + (lane & 15);
        int colb = kk * 64 + (lane >> 4) * 16;
        a[f] = *(const s16x8*)((const char*)As + row * 128 +
                               (colb ^ ((row & 7) << 4)));
      }
#pragma unroll
      for (int f = 0; f < 4; ++f) {
        int row = wn + f * 16 + (lane & 15);
        int colb = kk * 64 + (lane >> 4) * 16;
        b[f] = *(const s16x8*)((const char*)Bs + row * 128 +
                               (colb ^ ((row & 7) << 4)));
      }
#pragma unroll
      for (int fm = 0; fm < 4; ++fm)
#pragma unroll
        for (int fn = 0; fn < 4; ++fn)
          acc[fm][fn] = __builtin_amdgcn_mfma_f32_16x16x32_bf16(
              a[fm], b[fn], acc[fm][fn], 0, 0, 0);
    }
    __syncthreads();
  }
#pragma unroll
  for (int fm = 0; fm < 4; ++fm) {
    int rbase = m0 + wm + fm * 16 + (lane >> 4) * 4;
#pragma unroll
    for (int fn = 0; fn < 4; ++fn) {
      int col = n0 + wn + fn * 16 + (lane & 15);
      float bv = bias[col];
#pragma unroll
      for (int v = 0; v < 4; ++v) {
        int row = rbase + v;
        if (row < NN) {
          float xv = acc[fm][fn][v] + bv;
          xv = xv > 0.f ? xv : 0.2f * xv;
          if constexpr (OUTF32)
            ((float*)outp)[(size_t)g * NN * COUT + (size_t)row * COUT + col] = xv;
          else
            ((unsigned short*)outp)[(size_t)g * NN * COUT + (size_t)row * COUT +
                                    col] = f2bf(xv);
        }
      }
    }
  }
}

extern "C" void kernel_launch(void* const* d_in, const int* in_sizes, int n_in,
                              void* d_out, int out_size, void* d_ws, size_t ws_size,
                              hipStream_t stream) {
  const float* x  = (const float*)d_in[0];
  const int* ei   = (const int*)d_in[1];
  const int* etp  = (const int*)d_in[2];
  const float* W0 = (const float*)d_in[3];
  const float* r0 = (const float*)d_in[4];
  const float* b0 = (const float*)d_in[5];
  const float* W1 = (const float*)d_in[6];
  const float* r1 = (const float*)d_in[7];
  const float* b1 = (const float*)d_in[8];
  const float* W2 = (const float*)d_in[9];
  const float* r2 = (const float*)d_in[10];
  const float* b2 = (const float*)d_in[11];

  char* p = (char*)d_ws;
  unsigned short* agg = (unsigned short*)p; p += (size_t)2 * 8 * NN * 256 * 2;  // 164 MB
  unsigned short* hX  = (unsigned short*)p; p += (size_t)2 * NN * 256 * 2;      // h0 then h_b
  unsigned short* h_a = (unsigned short*)p; p += (size_t)2 * NN * 256 * 2;
  int* cnt  = (int*)p; p += (size_t)2 * NR * 4;
  int* off  = (int*)p; p += (size_t)2 * NR * 4;
  int* btot = (int*)p; p += (size_t)2 * NB * 4;
  int* bof  = (int*)p; p += (size_t)2 * NB * 4;
  int* ssrc = (int*)p; p += (size_t)2 * EE * 4;
  unsigned short* bt0 = (unsigned short*)p; p += (size_t)256 * 1152 * 2;
  unsigned short* bt1 = (unsigned short*)p; p += (size_t)256 * 2304 * 2;
  unsigned short* bt2 = (unsigned short*)p; p += (size_t)128 * 2304 * 2;

  // weight panels (graph-independent)
  k_bt<<<(256 * 1152 + 255) / 256, 256, 0, stream>>>(W0, r0, bt0, 128, 256, 1152);
  k_bt<<<(256 * 2304 + 255) / 256, 256, 0, stream>>>(W1, r1, bt1, 256, 256, 2304);
  k_bt<<<(128 * 2304 + 255) / 256, 256, 0, stream>>>(W2, r2, bt2, 256, 128, 2304);

  // edge sort (both graphs batched)
  hipMemsetAsync(cnt, 0, (size_t)2 * NR * 4, stream);
  k_count<<<2 * EE / 256, 256, 0, stream>>>(ei, etp, cnt);
  k_scan1<<<dim3(NB, 2), 1024, 0, stream>>>(cnt, off, btot);
  k_scan2<<<1, 128, 0, stream>>>(btot, bof);
  k_scan3<<<dim3(NB, 2), 1024, 0, stream>>>(off, bof);
  k_cvt<<<2 * NN * 128 / 4 / 256, 256, 0, stream>>>(x, hX);
  k_scatter<<<2 * EE / 256, 256, 0, stream>>>(ei, etp, off, ssrc);

  // layer 0: 128 -> 256
  k_gather<128><<<dim3((NN + 3) / 4, 2), 256, 0, stream>>>(ssrc, off, hX, agg);
  k_gemm<128, 256, false><<<dim3(157, 2, 2), 256, 0, stream>>>(agg, hX, bt0, b0, h_a);
  // layer 1: 256 -> 256
  k_gather<256><<<dim3((NN + 3) / 4, 2), 256, 0, stream>>>(ssrc, off, h_a, agg);
  k_gemm<256, 256, false><<<dim3(157, 2, 2), 256, 0, stream>>>(agg, h_a, bt1, b1, hX);
  // layer 2: 256 -> 128
  k_gather<256><<<dim3((NN + 3) / 4, 2), 256, 0, stream>>>(ssrc, off, hX, agg);
  k_gemm<256, 128, true><<<dim3(157, 1, 2), 256, 0, stream>>>(agg, hX, bt2, b2, d_out);
}